// Round 17
// baseline (171.034 us; speedup 1.0000x reference)
//
#include <hip/hip_runtime.h>
#include <cmath>

typedef unsigned short u16;
typedef unsigned int   u32;
typedef __attribute__((ext_vector_type(8))) short bf16x8;  // 8 bf16 in 4 VGPRs
typedef __attribute__((ext_vector_type(4))) float f32x4;   // MFMA accumulator

#define DEV __device__ __forceinline__
#define MFMA(a,b,c) __builtin_amdgcn_mfma_f32_16x16x32_bf16((a),(b),(c),0,0,0)

// async global->LDS, 16B per lane: lane l writes dst + l*16 bytes (dst wave-uniform;
// global source address is PER-LANE)
#define GLOAD16(dst, src) __builtin_amdgcn_global_load_lds( \
    (const __attribute__((address_space(1))) void*)(src), \
    (__attribute__((address_space(3))) void*)(dst), 16, 0, 0)

// ---- bf16 helpers (RNE) ----
DEV u16 f2bf(float x){ union{float f;u32 u;} v; v.f=x; u32 r=v.u+0x7FFFu+((v.u>>16)&1u); return (u16)(r>>16); }
DEV float bf2f(u16 h){ union{u32 u;float f;} v; v.u=((u32)h)<<16; return v.f; }

// LDS read-side swizzle: within a row (64 elems = 8 col-blocks of 8), XOR the
// col-block with row&7. Same involution on the gload SOURCE col, LDS dest
// linear (rule #21). HW-verified rounds 7-16: conflicts=0, absmax unchanged.
DEV int swz(int row, int cb){ return row*64 + ((cb ^ (row&7))*8); }

// stage one 64x64 unit: 512 threads x 16B; dst linear, src col inverse-swizzled
#define STGU(arr, slotsz, slot, j, P, k0) GLOAD16( \
    &(arr)[(slot)*(slotsz) + ((j)*64 + w*8)*64], \
    (P) + (size_t)((j)*64 + srow_)*1024 + (k0) + scol_)

// ============================================================================
// GEMM core v2 (128x256, round-12 proven — used by k_out): BK=64, K=1024,
// 512 thr = 8 waves (2M x 4N). 3 LDS slots, stage 2 tiles ahead, vmcnt(6)
// once/tile, ONE barrier/tile, compiler-scheduled interior.
// ============================================================================
#define GEMM_CORE_128x256(As, Bs, Ap, Bp, acc) do{ \
    const int srow_ = w*8 + (l>>3); \
    const int scol_ = ((l&7) ^ (l>>3))*8; \
    STGU(Bs,256*64,0,0,Bp,0); STGU(Bs,256*64,0,1,Bp,0); STGU(Bs,256*64,0,2,Bp,0); \
    STGU(Bs,256*64,0,3,Bp,0); STGU(As,128*64,0,0,Ap,0); STGU(As,128*64,0,1,Ap,0); \
    STGU(Bs,256*64,1,0,Bp,64); STGU(Bs,256*64,1,1,Bp,64); STGU(Bs,256*64,1,2,Bp,64); \
    STGU(Bs,256*64,1,3,Bp,64); STGU(As,128*64,1,0,Ap,64); STGU(As,128*64,1,1,Ap,64); \
    asm volatile("s_waitcnt vmcnt(6)" ::: "memory"); \
    __builtin_amdgcn_s_barrier(); \
    __builtin_amdgcn_sched_barrier(0); \
    for(int kt=0; kt<16; ++kt){ \
        const int sl = kt % 3; \
        const int st = (kt+2) % 3; \
        const int k2 = (kt+2)*64; \
        const u16* Asl = (As) + sl*(128*64); \
        const u16* Bsl = (Bs) + sl*(256*64); \
        bf16x8 bf_[4][2], af_[4][2]; \
        _Pragma("unroll") \
        for(int nt=0;nt<4;++nt) \
            _Pragma("unroll") \
            for(int ks=0;ks<2;++ks) \
                bf_[nt][ks] = *(const bf16x8*)&Bsl[swz(64*wc+16*nt+c, 4*ks+g)]; \
        _Pragma("unroll") \
        for(int mt=0;mt<4;++mt) \
            _Pragma("unroll") \
            for(int ks=0;ks<2;++ks) \
                af_[mt][ks] = *(const bf16x8*)&Asl[swz(64*wr+16*mt+c, 4*ks+g)]; \
        if (kt<=13){ STGU(Bs,256*64,st,0,Bp,k2); STGU(Bs,256*64,st,1,Bp,k2); STGU(Bs,256*64,st,2,Bp,k2); \
                     STGU(Bs,256*64,st,3,Bp,k2); STGU(As,128*64,st,0,Ap,k2); STGU(As,128*64,st,1,Ap,k2); } \
        _Pragma("unroll") \
        for(int mt=0;mt<4;++mt) \
            _Pragma("unroll") \
            for(int nt=0;nt<4;++nt) \
                _Pragma("unroll") \
                for(int ks=0;ks<2;++ks) \
                    acc[mt][nt] = MFMA(af_[mt][ks], bf_[nt][ks], acc[mt][nt]); \
        if (kt<=13)      { asm volatile("s_waitcnt vmcnt(6)" ::: "memory"); } \
        else if (kt==14) { asm volatile("s_waitcnt vmcnt(0)" ::: "memory"); } \
        __builtin_amdgcn_s_barrier(); \
        __builtin_amdgcn_sched_barrier(0); \
    } \
}while(0)

// ============================================================================
// k_prep: ALL prep fused into one dispatch.
// ============================================================================
__global__ __launch_bounds__(256) void k_prep(const float* __restrict__ X,
        const float* __restrict__ Wq, const float* __restrict__ Wk,
        const float* __restrict__ Wv, const float* __restrict__ Wf,
        const float* __restrict__ proj,
        u16* __restrict__ Xb, u16* __restrict__ WT, u16* __restrict__ Wfh,
        u16* __restrict__ pPh){
    const int bid = blockIdx.x, tid = threadIdx.x;
    if (bid < 4096){
        __shared__ float t[32][33];
        const int which = bid >> 10, bb = bid & 1023;
        const float* in = (which==0) ? Wq : (which==1) ? Wk : (which==2) ? Wv : Wf;
        u16* hi = (which==3) ? Wfh : (WT + (size_t)which*1048576);
        const int r0 = (bb>>5)*32, c0 = (bb&31)*32;
        const int lr = tid>>3, lc = (tid&7)*4;
        float4 v = *(const float4*)(in + (size_t)(r0+lr)*1024 + c0 + lc);
        t[lr][lc]=v.x; t[lr][lc+1]=v.y; t[lr][lc+2]=v.z; t[lr][lc+3]=v.w;
        __syncthreads();
        ushort4 o;
        o.x=f2bf(t[lc+0][lr]); o.y=f2bf(t[lc+1][lr]);
        o.z=f2bf(t[lc+2][lr]); o.w=f2bf(t[lc+3][lr]);
        *(ushort4*)(hi + (size_t)(c0+lr)*1024 + r0+lc) = o;
    } else if (bid < 12288){
        size_t i = ((size_t)(bid-4096)*256 + tid)*4;
        float4 v = *(const float4*)(X+i);
        ushort4 o; o.x=f2bf(v.x); o.y=f2bf(v.y); o.z=f2bf(v.z); o.w=f2bf(v.w);
        *(ushort4*)(Xb+i) = o;
    } else {
        int idx = (bid-12288)*256 + tid;          // 0..16383
        int e = idx&7, l = (idx>>3)&63, f = idx>>9;
        int nt = f>>1, ks = f&1;
        int d = 32*ks + 8*(l>>4) + e;
        int m = 16*nt + (l&15);
        pPh[idx] = f2bf(proj[d*256 + m]);
    }
}

// ============================================================================
// k_qkv (256x256 core): C = X @ {Wq,Wk,Wv}, BM=BN=256, BK=64, 2 LDS slots
// (128KB). 512 thr = 8 waves (2M x 4N), per-wave 128x64 out = acc[8][4].
// Per tile: stage ALL 8 units of tile kt+1 at tile top (issue->certify ~ one
// full MFMA region ~2400cy >> 900 HBM), ONE vmcnt(0)+barrier at tile end,
// compiler-scheduled interior, setprio around MFMA.
// grid (32, 12) = 384: y/4 = wsel, y%4 = 256-col block.
// ============================================================================
__global__ __launch_bounds__(512,2) void k_qkv(const u16* __restrict__ Xb, const u16* __restrict__ WT,
        const float* __restrict__ bq, const float* __restrict__ bk, const float* __restrict__ bv,
        u16* __restrict__ Qb, u16* __restrict__ Kb, u16* __restrict__ VT){
    __shared__ u16 As[2*256*64];   // 64KB
    __shared__ u16 Bs[2*256*64];   // 64KB
    const int bx = blockIdx.x, y = blockIdx.y;
    const int wsel = y>>2, nb = y&3;
    const int tid = threadIdx.x, w = tid>>6, l = tid&63, g = l>>4, c = l&15;
    const int wr = w>>2, wc = w&3;
    const u16* Ap = Xb + (size_t)bx*256*1024;
    const u16* Bp = WT + (size_t)wsel*1048576 + (size_t)nb*256*1024;
    const int srow_ = w*8 + (l>>3);
    const int scol_ = ((l&7) ^ (l>>3))*8;
    f32x4 acc[8][4];
    #pragma unroll
    for(int mt=0;mt<8;++mt)
        #pragma unroll
        for(int nt=0;nt<4;++nt) acc[mt][nt] = f32x4{0.f,0.f,0.f,0.f};
    // prologue: tile0 -> slot0 (8 units)
    STGU(Bs,256*64,0,0,Bp,0); STGU(Bs,256*64,0,1,Bp,0);
    STGU(Bs,256*64,0,2,Bp,0); STGU(Bs,256*64,0,3,Bp,0);
    STGU(As,256*64,0,0,Ap,0); STGU(As,256*64,0,1,Ap,0);
    STGU(As,256*64,0,2,Ap,0); STGU(As,256*64,0,3,Ap,0);
    asm volatile("s_waitcnt vmcnt(0)" ::: "memory");
    __builtin_amdgcn_s_barrier();
    __builtin_amdgcn_sched_barrier(0);
    for(int kt=0; kt<16; ++kt){
        const int cur = kt&1, nx = cur^1, k2 = (kt+1)*64;
        const bool more = kt < 15;
        const u16* Asl = As + cur*(256*64);
        const u16* Bsl = Bs + cur*(256*64);
        bf16x8 bf_[4][2];
        #pragma unroll
        for(int nt=0;nt<4;++nt)
            #pragma unroll
            for(int ks=0;ks<2;++ks)
                bf_[nt][ks] = *(const bf16x8*)&Bsl[swz(64*wc+16*nt+c, 4*ks+g)];
        if (more){
            STGU(Bs,256*64,nx,0,Bp,k2); STGU(Bs,256*64,nx,1,Bp,k2);
            STGU(Bs,256*64,nx,2,Bp,k2); STGU(Bs,256*64,nx,3,Bp,k2);
            STGU(As,256*64,nx,0,Ap,k2); STGU(As,256*64,nx,1,Ap,k2);
            STGU(As,256*64,nx,2,Ap,k2); STGU(As,256*64,nx,3,Ap,k2);
        }
        __builtin_amdgcn_s_setprio(1);
        #pragma unroll
        for(int mt=0;mt<8;++mt){
            bf16x8 a0 = *(const bf16x8*)&Asl[swz(128*wr+16*mt+c, g)];
            bf16x8 a1 = *(const bf16x8*)&Asl[swz(128*wr+16*mt+c, 4+g)];
            #pragma unroll
            for(int nt=0;nt<4;++nt){
                acc[mt][nt] = MFMA(a0, bf_[nt][0], acc[mt][nt]);
                acc[mt][nt] = MFMA(a1, bf_[nt][1], acc[mt][nt]);
            }
        }
        __builtin_amdgcn_s_setprio(0);
        if (more) asm volatile("s_waitcnt vmcnt(0)" ::: "memory");
        __builtin_amdgcn_s_barrier();
        __builtin_amdgcn_sched_barrier(0);
    }
    const int n0 = nb*256 + 64*wc;    // col within this wsel's 1024
    const int b = bx>>4;
    if (wsel < 2){
        u16* Out = wsel ? Kb : Qb;
        const float* bias = wsel ? bk : bq;
        float bb[4];
        #pragma unroll
        for(int nt=0;nt<4;++nt) bb[nt] = bias[n0+16*nt+c];
        #pragma unroll
        for(int mt=0;mt<8;++mt){
            #pragma unroll
            for(int nt=0;nt<4;++nt)
                #pragma unroll
                for(int r=0;r<4;++r) acc[mt][nt][r] += bb[nt];
            // wave's 64 cols are one head -> norm over nt(4) x shfl16
            #pragma unroll
            for(int r=0;r<4;++r){
                float ss = 0.f;
                #pragma unroll
                for(int nt=0;nt<4;++nt){ float vv = acc[mt][nt][r]; ss += vv*vv; }
                ss += __shfl_xor(ss,1); ss += __shfl_xor(ss,2);
                ss += __shfl_xor(ss,4); ss += __shfl_xor(ss,8);
                float sc = 1.f/(sqrtf(ss)+1e-6f);
                #pragma unroll
                for(int nt=0;nt<4;++nt) acc[mt][nt][r] *= sc;
            }
            const int rowb = bx*256 + 128*wr + 16*mt + 4*g;
            #pragma unroll
            for(int nt=0;nt<4;++nt)
                #pragma unroll
                for(int r=0;r<4;++r)
                    Out[(size_t)(rowb+r)*1024 + n0 + 16*nt + c] = f2bf(acc[mt][nt][r]);
        }
    } else {
        const int h = nb*4 + wc;
        float bb[4];
        #pragma unroll
        for(int nt=0;nt<4;++nt) bb[nt] = bv[n0+16*nt+c];
        #pragma unroll
        for(int mt=0;mt<8;++mt)
            #pragma unroll
            for(int nt=0;nt<4;++nt){
                const int d = 16*nt + c;
                const int s0m = (bx&15)*256 + 128*wr + 16*mt + 4*g;
                ushort4 o;
                o.x = f2bf(acc[mt][nt][0]+bb[nt]); o.y = f2bf(acc[mt][nt][1]+bb[nt]);
                o.z = f2bf(acc[mt][nt][2]+bb[nt]); o.w = f2bf(acc[mt][nt][3]+bb[nt]);
                *(ushort4*)(VT + ((size_t)(b*16+h)*64 + d)*4096 + s0m) = o;
            }
    }
}

// ============================================================================
// k_kv v2 (round-15 proven): grid (8, 32), 512 thr = 8 waves. Split-K 8 chunks
// of 512 s; 4 t-iters of 128 s-rows. pPh staged in LDS once.
// ============================================================================
__global__ __launch_bounds__(512) void k_kv(const u16* __restrict__ Kb,
        const u16* __restrict__ pPh,
        const float* __restrict__ mask, const u16* __restrict__ VT,
        float* __restrict__ KVpart, float* __restrict__ Zpart){
    __shared__ u16 pps[16384];        // 32KB, linear copy of pPh
    __shared__ u16 phiT[256][136];    // [m][s 128], pad 136
    __shared__ u16 Vs[64][136];       // [d][s 128]
    __shared__ float zbuf[8][256];
    const int chunk = blockIdx.x, bh = blockIdx.y;
    const int b = bh>>4, h = bh&15;
    const int tid = threadIdx.x, w = tid>>6, l = tid&63, g = l>>4, c = l&15;
    // stage pps once
    #pragma unroll
    for(int j2=0;j2<4;++j2){
        const int base = (j2*8 + w)*512;
        GLOAD16(pps + base, pPh + base + l*8);
    }
    f32x4 kv[2][4];
    #pragma unroll
    for(int mt=0;mt<2;++mt) for(int dt=0;dt<4;++dt) kv[mt][dt] = f32x4{0.f,0.f,0.f,0.f};
    float zacc[16];
    #pragma unroll
    for(int nt=0;nt<16;++nt) zacc[nt]=0.f;
    const int vd = tid>>3, vs8 = (tid&7)*16;
    asm volatile("s_waitcnt vmcnt(0)" ::: "memory");
    __syncthreads();                       // pps staged
    for(int t=0;t<4;++t){
        const int s0 = chunk*512 + t*128;
        { // stage V tile [64 d][128 s] (reg path; 512 thr x 16 u16)
            const u16* pv = VT + ((size_t)bh*64 + vd)*4096 + s0 + vs8;
            uint4 v0 = *(const uint4*)pv, v1 = *(const uint4*)(pv+8);
            *(uint4*)&Vs[vd][vs8] = v0; *(uint4*)&Vs[vd][vs8+8] = v1;
        }
        // phase A: u = K_head @ proj (wave w -> s rows s0+16w..+15), pps-resident
        f32x4 ph[16];
        #pragma unroll
        for(int nt=0;nt<16;++nt) ph[nt] = f32x4{0.f,0.f,0.f,0.f};
        #pragma unroll
        for(int ks=0;ks<2;++ks){
            const int srow = s0 + 16*w + c;
            bf16x8 ah = *(const bf16x8*)(Kb + (size_t)(b*4096+srow)*1024 + h*64 + 32*ks + 8*g);
            #pragma unroll
            for(int nt=0;nt<16;++nt){
                bf16x8 bh8 = *(const bf16x8*)(pps + ((nt*2+ks)*64 + l)*8);
                ph[nt] = MFMA(ah, bh8, ph[nt]);
            }
        }
        float mk[4];
        #pragma unroll
        for(int r=0;r<4;++r) mk[r] = mask[b*4096 + s0 + 16*w + 4*g + r];
        #pragma unroll
        for(int nt=0;nt<16;++nt){
            float zs = 0.f;
            #pragma unroll
            for(int r=0;r<4;++r){
                float phv = __expf(ph[nt][r]-0.5f)*0.0625f*mk[r];
                phiT[c+16*nt][16*w+4*g+r] = f2bf(phv);
                zs += phv;
            }
            zacc[nt] += zs;
        }
        __syncthreads();               // phiT + Vs written
        // phase B: KV += phiT(A, m rows 32w..) x Vs(B, d cols), K=128
        #pragma unroll
        for(int ks=0;ks<4;++ks){
            bf16x8 afr[2], bfr[4];
            #pragma unroll
            for(int mt=0;mt<2;++mt) afr[mt] = *(const bf16x8*)&phiT[32*w+16*mt+c][32*ks+8*g];
            #pragma unroll
            for(int dt=0;dt<4;++dt) bfr[dt] = *(const bf16x8*)&Vs[16*dt+c][32*ks+8*g];
            #pragma unroll
            for(int mt=0;mt<2;++mt)
                #pragma unroll
                for(int dt=0;dt<4;++dt)
                    kv[mt][dt] = MFMA(afr[mt], bfr[dt], kv[mt][dt]);
        }
        __syncthreads();               // phase-B reads done before next overwrite
    }
    // Z partial
    #pragma unroll
    for(int nt=0;nt<16;++nt){
        float z = zacc[nt];
        z += __shfl_xor(z,16); z += __shfl_xor(z,32);
        if (g==0) zbuf[w][c+16*nt] = z;
    }
    __syncthreads();
    if (tid < 256){
        float z = 0.f;
        #pragma unroll
        for(int ww=0;ww<8;++ww) z += zbuf[ww][tid];
        Zpart[((size_t)bh*8+chunk)*256 + tid] = z;
    }
    float* kout = KVpart + ((size_t)bh*8+chunk)*16384;   // [256 m][64 d]
    #pragma unroll
    for(int mt=0;mt<2;++mt)
        #pragma unroll
        for(int dt=0;dt<4;++dt)
            #pragma unroll
            for(int r=0;r<4;++r)
                kout[(32*w+16*mt+4*g+r)*64 + 16*dt + c] = kv[mt][dt][r];
}

// ============================================================================
// k_kvreduce (round-15 proven): 512 blocks x 256 threads, one float4/thread.
// ============================================================================
__global__ __launch_bounds__(256) void k_kvreduce(const float* __restrict__ KVpart,
        const float* __restrict__ Zpart, u16* __restrict__ KVT, float* __restrict__ Z){
    const int gid = blockIdx.x*256 + threadIdx.x;      // 0..131071
    const int bh = gid >> 12;                          // 4096 float4 per bh
    const int i0 = (gid & 4095) * 4;                   // element idx in [256m][64d]
    float4 s = {0.f,0.f,0.f,0.f};
    const float* base = KVpart + (size_t)bh*8*16384 + i0;
    #pragma unroll
    for(int ch=0; ch<8; ++ch){
        float4 v = *(const float4*)(base + (size_t)ch*16384);
        s.x+=v.x; s.y+=v.y; s.z+=v.z; s.w+=v.w;
    }
    const int m = i0 >> 6, d = i0 & 63;                // 4 consecutive d, same m
    u16* dst = KVT + ((size_t)bh*64 + d)*256 + m;
    dst[0]   = f2bf(s.x);
    dst[256] = f2bf(s.y);
    dst[512] = f2bf(s.z);
    dst[768] = f2bf(s.w);
    if (gid < 8192){
        const int zbh = gid >> 8, zm = gid & 255;
        float z = 0.f;
        #pragma unroll
        for(int ch=0; ch<8; ++ch) z += Zpart[((size_t)zbh*8+ch)*256 + zm];
        Z[zbh*256 + zm] = z;
    }
}

// ============================================================================
// k_attn v2 (round-15 proven): grid (8, 32), 512 thr = 8 waves.
// KVT (32KB swizzled) + pPh (32KB) + Z staged in LDS once; 4 tiles x 128 rows.
// ============================================================================
__global__ __launch_bounds__(512) void k_attn(const u16* __restrict__ Qb,
        const u16* __restrict__ pPh,
        const u16* __restrict__ KVT, const float* __restrict__ Z, u16* __restrict__ attn){
    __shared__ u16 kvs[64*256];       // 32KB, row d, swizzled col-blocks
    __shared__ u16 pps[16384];        // 32KB, linear copy of pPh
    __shared__ u16 phi[128][264];     // 67.5KB
    __shared__ float Zs[256];
    const int bx = blockIdx.x, bh = blockIdx.y;
    const int b = bh>>4, h = bh&15;
    const int tid = threadIdx.x, w = tid>>6, l = tid&63, g = l>>4, c = l&15;
    if (tid < 256) Zs[tid] = Z[bh*256 + tid];
    // stage kvs: 32 gload units of 2 rows; dst linear, src col-block pre-swizzled
    #pragma unroll
    for(int j2=0;j2<4;++j2){
        const int base_row = (j2*8 + w)*2;
        const int row = base_row + (l>>5), cb = l&31;
        GLOAD16(kvs + base_row*256,
                KVT + (size_t)bh*16384 + row*256 + ((cb ^ (row&7))*8));
    }
    // stage pps: straight linear copy
    #pragma unroll
    for(int j2=0;j2<4;++j2){
        const int base = (j2*8 + w)*512;
        GLOAD16(pps + base, pPh + base + l*8);
    }
    asm volatile("s_waitcnt vmcnt(0)" ::: "memory");
    __syncthreads();

    for(int t=0;t<4;++t){
        const int s0 = bx*512 + t*128;
        // phiQ: u = Q_head @ proj (wave w -> s rows s0+16w .. +15)
        f32x4 ph[16];
        #pragma unroll
        for(int nt=0;nt<16;++nt) ph[nt] = f32x4{0.f,0.f,0.f,0.f};
        #pragma unroll
        for(int ks=0;ks<2;++ks){
            const int srow = s0 + 16*w + c;
            bf16x8 ah = *(const bf16x8*)(Qb + (size_t)(b*4096+srow)*1024 + h*64 + 32*ks + 8*g);
            #pragma unroll
            for(int nt=0;nt<16;++nt){
                bf16x8 bh8 = *(const bf16x8*)(pps + ((nt*2+ks)*64 + l)*8);
                ph[nt] = MFMA(ah, bh8, ph[nt]);
            }
        }
        float den[4] = {0.f,0.f,0.f,0.f};
        #pragma unroll
        for(int nt=0;nt<16;++nt){
            float zv = Zs[c+16*nt];
            #pragma unroll
            for(int r=0;r<4;++r){
                float phv = __expf(ph[nt][r]-0.5f)*0.0625f;
                den[r] += phv*zv;
                phi[16*w+4*g+r][c+16*nt] = f2bf(phv);
            }
        }
        #pragma unroll
        for(int r=0;r<4;++r){
            den[r] += __shfl_xor(den[r],1); den[r] += __shfl_xor(den[r],2);
            den[r] += __shfl_xor(den[r],4); den[r] += __shfl_xor(den[r],8);
            den[r] += 1e-6f;
        }
        __syncthreads();              // phi written
        f32x4 nm[4];
        #pragma unroll
        for(int dt=0;dt<4;++dt) nm[dt] = f32x4{0.f,0.f,0.f,0.f};
        #pragma unroll
        for(int j=0;j<8;++j){
            bf16x8 af = *(const bf16x8*)&phi[16*w+c][32*j+8*g];
            #pragma unroll
            for(int dt=0;dt<4;++dt){
                const int row = 16*dt + c, cb = 4*j + g;
                bf16x8 bfr = *(const bf16x8*)(kvs + row*256 + ((cb ^ (row&7))*8));
                nm[dt] = MFMA(af, bfr, nm[dt]);
            }
        }
        #pragma unroll
        for(int dt=0;dt<4;++dt)
            #pragma unroll
            for(int r=0;r<4;++r){
                const int srow = s0 + 16*w + 4*g + r;
                attn[(size_t)(b*4096+srow)*1024 + h*64 + 16*dt + c] = f2bf(nm[dt][r]*8.f/den[r]);
            }
        __syncthreads();              // phi reads done before next tile's writes
    }
}

// ============================================================================
// k_out: out = attn(bf16) @ WfT(bf16) + bf, fp32 out. GEMM core v2 (128x256).
// grid (64,4) = 256 = 1 exact CU round.
// ============================================================================
__global__ __launch_bounds__(512,2) void k_out(const u16* __restrict__ attn,
        const u16* __restrict__ Wh, const float* __restrict__ bfb, float* __restrict__ out){
    __shared__ u16 As[3*128*64];   // 48KB
    __shared__ u16 Bs[3*256*64];   // 96KB
    const int bx = blockIdx.x, by = blockIdx.y;
    const int tid = threadIdx.x, w = tid>>6, l = tid&63, g = l>>4, c = l&15;
    const int wr = w>>2, wc = w&3;
    const u16* Ap = attn + (size_t)bx*128*1024;
    const u16* Bp = Wh + (size_t)by*256*1024;
    f32x4 acc[4][4];
    #pragma unroll
    for(int mt=0;mt<4;++mt)
        #pragma unroll
        for(int nt=0;nt<4;++nt) acc[mt][nt] = f32x4{0.f,0.f,0.f,0.f};

    GEMM_CORE_128x256(As, Bs, Ap, Bp, acc);

    const int n0 = by*256 + 64*wc;
    #pragma unroll
    for(int mt=0;mt<4;++mt){
        const int rowb = bx*128 + 64*wr + 16*mt + 4*g;
        #pragma unroll
        for(int nt=0;nt<4;++nt){
            const float bb = bfb[n0+16*nt+c];
            #pragma unroll
            for(int r=0;r<4;++r)
                out[(size_t)(rowb+r)*1024 + n0 + 16*nt + c] = acc[mt][nt][r] + bb;
        }
    }
}

// ============================================================================
extern "C" void kernel_launch(void* const* d_in, const int* in_sizes, int n_in,
                              void* d_out, int out_size, void* d_ws, size_t ws_size,
                              hipStream_t stream){
    (void)in_sizes; (void)n_in; (void)out_size;
    const float* X    = (const float*)d_in[0];
    const float* mask = (const float*)d_in[1];
    const float* Wq   = (const float*)d_in[2];
    const float* bq   = (const float*)d_in[3];
    const float* Wk   = (const float*)d_in[4];
    const float* bk   = (const float*)d_in[5];
    const float* Wv   = (const float*)d_in[6];
    const float* bv   = (const float*)d_in[7];
    const float* Wf   = (const float*)d_in[8];
    const float* bfb  = (const float*)d_in[9];
    const float* proj = (const float*)d_in[10];
    float* out = (float*)d_out;

    char* w = (char*)d_ws;
    size_t off = 0;
    auto alloc = [&](size_t n)->void*{ void* p = w + off; off = (off + n + 255) & ~(size_t)255; return p; };
    u16*   Xb     = (u16*)  alloc((size_t)8192*1024*2);    // X bf16
    u16*   WT     = (u16*)  alloc((size_t)3*1048576*2);    // Wq,Wk,Wv transposed [n][k]
    u16*   Wfh    = (u16*)  alloc((size_t)1048576*2);      // WfT
    u16*   pPh    = (u16*)  alloc(16384*2);                // proj packed (bf16)
    u16*   Qb     = (u16*)  alloc((size_t)8192*1024*2);    // normalized Q bf16
    u16*   Kb     = (u16*)  alloc((size_t)8192*1024*2);    // normalized K bf16
    u16*   VT     = (u16*)  alloc((size_t)32*64*4096*2);   // V^T per head bf16
    float* KVpart = (float*)alloc((size_t)32*8*16384*4);   // split-K KV partials
    float* Zpart  = (float*)alloc((size_t)32*8*256*4);
    u16*   KVT    = (u16*)  alloc((size_t)32*64*256*2);    // KV^T [d][m] bf16
    float* Zr     = (float*)alloc((size_t)32*256*4);
    u16*   attnB  = (u16*)  alloc((size_t)8192*1024*2);    // attn bf16
    if (off > ws_size) return;  // ws too small: fail cleanly (output stays zero)

    k_prep<<<dim3(12352), 256, 0, stream>>>(X, Wq, Wk, Wv, Wf, proj, Xb, WT, Wfh, pPh);
    k_qkv<<<dim3(32,12), 512, 0, stream>>>(Xb, WT, bq, bk, bv, Qb, Kb, VT);
    k_kv<<<dim3(8,32), 512, 0, stream>>>(Kb, pPh, mask, VT, KVpart, Zpart);
    k_kvreduce<<<dim3(512), 256, 0, stream>>>(KVpart, Zpart, KVT, Zr);
    k_attn<<<dim3(8,32), 512, 0, stream>>>(Qb, pPh, KVT, Zr, attnB);
    k_out<<<dim3(64,4), 512, 0, stream>>>(attnB, Wfh, bfb, out);
}

// Round 18
// 157.469 us; speedup vs baseline: 1.0861x; 1.0861x over previous
//
#include <hip/hip_runtime.h>
#include <cmath>

typedef unsigned short u16;
typedef unsigned int   u32;
typedef __attribute__((ext_vector_type(8))) short bf16x8;  // 8 bf16 in 4 VGPRs
typedef __attribute__((ext_vector_type(4))) float f32x4;   // MFMA accumulator

#define DEV __device__ __forceinline__
#define MFMA(a,b,c) __builtin_amdgcn_mfma_f32_16x16x32_bf16((a),(b),(c),0,0,0)

// async global->LDS, 16B per lane: lane l writes dst + l*16 bytes (dst wave-uniform;
// global source address is PER-LANE)
#define GLOAD16(dst, src) __builtin_amdgcn_global_load_lds( \
    (const __attribute__((address_space(1))) void*)(src), \
    (__attribute__((address_space(3))) void*)(dst), 16, 0, 0)

// ---- bf16 helpers (RNE) ----
DEV u16 f2bf(float x){ union{float f;u32 u;} v; v.f=x; u32 r=v.u+0x7FFFu+((v.u>>16)&1u); return (u16)(r>>16); }
DEV float bf2f(u16 h){ union{u32 u;float f;} v; v.u=((u32)h)<<16; return v.f; }

// LDS read-side swizzle: within a row (64 elems = 8 col-blocks of 8), XOR the
// col-block with row&7. Same involution on the gload SOURCE col, LDS dest
// linear (rule #21). HW-verified rounds 7-17: conflicts=0, absmax unchanged.
DEV int swz(int row, int cb){ return row*64 + ((cb ^ (row&7))*8); }

// stage one 64x64 unit: 512 threads x 16B; dst linear, src col inverse-swizzled
#define STGU(arr, slotsz, slot, j, P, k0) GLOAD16( \
    &(arr)[(slot)*(slotsz) + ((j)*64 + w*8)*64], \
    (P) + (size_t)((j)*64 + srow_)*1024 + (k0) + scol_)

// ============================================================================
// GEMM core v2 (de-poisoned schedule, round-12 proven): BM=128 x BN=256,
// BK=64, K=1024 (16 tiles), 512 thr = 8 waves (2M x 4N). 3 LDS slots, stage
// 2 tiles ahead (6 gloads/tile), vmcnt(6) once/tile (never drained in-loop),
// ONE barrier/tile, compiler-scheduled interior.
// ============================================================================
#define GEMM_CORE_128x256(As, Bs, Ap, Bp, acc) do{ \
    const int srow_ = w*8 + (l>>3); \
    const int scol_ = ((l&7) ^ (l>>3))*8; \
    STGU(Bs,256*64,0,0,Bp,0); STGU(Bs,256*64,0,1,Bp,0); STGU(Bs,256*64,0,2,Bp,0); \
    STGU(Bs,256*64,0,3,Bp,0); STGU(As,128*64,0,0,Ap,0); STGU(As,128*64,0,1,Ap,0); \
    STGU(Bs,256*64,1,0,Bp,64); STGU(Bs,256*64,1,1,Bp,64); STGU(Bs,256*64,1,2,Bp,64); \
    STGU(Bs,256*64,1,3,Bp,64); STGU(As,128*64,1,0,Ap,64); STGU(As,128*64,1,1,Ap,64); \
    asm volatile("s_waitcnt vmcnt(6)" ::: "memory"); \
    __builtin_amdgcn_s_barrier(); \
    __builtin_amdgcn_sched_barrier(0); \
    for(int kt=0; kt<16; ++kt){ \
        const int sl = kt % 3; \
        const int st = (kt+2) % 3; \
        const int k2 = (kt+2)*64; \
        const u16* Asl = (As) + sl*(128*64); \
        const u16* Bsl = (Bs) + sl*(256*64); \
        bf16x8 bf_[4][2], af_[4][2]; \
        _Pragma("unroll") \
        for(int nt=0;nt<4;++nt) \
            _Pragma("unroll") \
            for(int ks=0;ks<2;++ks) \
                bf_[nt][ks] = *(const bf16x8*)&Bsl[swz(64*wc+16*nt+c, 4*ks+g)]; \
        _Pragma("unroll") \
        for(int mt=0;mt<4;++mt) \
            _Pragma("unroll") \
            for(int ks=0;ks<2;++ks) \
                af_[mt][ks] = *(const bf16x8*)&Asl[swz(64*wr+16*mt+c, 4*ks+g)]; \
        if (kt<=13){ STGU(Bs,256*64,st,0,Bp,k2); STGU(Bs,256*64,st,1,Bp,k2); STGU(Bs,256*64,st,2,Bp,k2); \
                     STGU(Bs,256*64,st,3,Bp,k2); STGU(As,128*64,st,0,Ap,k2); STGU(As,128*64,st,1,Ap,k2); } \
        _Pragma("unroll") \
        for(int mt=0;mt<4;++mt) \
            _Pragma("unroll") \
            for(int nt=0;nt<4;++nt) \
                _Pragma("unroll") \
                for(int ks=0;ks<2;++ks) \
                    acc[mt][nt] = MFMA(af_[mt][ks], bf_[nt][ks], acc[mt][nt]); \
        if (kt<=13)      { asm volatile("s_waitcnt vmcnt(6)" ::: "memory"); } \
        else if (kt==14) { asm volatile("s_waitcnt vmcnt(0)" ::: "memory"); } \
        __builtin_amdgcn_s_barrier(); \
        __builtin_amdgcn_sched_barrier(0); \
    } \
}while(0)

// ============================================================================
// k_prep: ALL prep fused into one dispatch.
// ============================================================================
__global__ __launch_bounds__(256) void k_prep(const float* __restrict__ X,
        const float* __restrict__ Wq, const float* __restrict__ Wk,
        const float* __restrict__ Wv, const float* __restrict__ Wf,
        const float* __restrict__ proj,
        u16* __restrict__ Xb, u16* __restrict__ WT, u16* __restrict__ Wfh,
        u16* __restrict__ pPh){
    const int bid = blockIdx.x, tid = threadIdx.x;
    if (bid < 4096){
        __shared__ float t[32][33];
        const int which = bid >> 10, bb = bid & 1023;
        const float* in = (which==0) ? Wq : (which==1) ? Wk : (which==2) ? Wv : Wf;
        u16* hi = (which==3) ? Wfh : (WT + (size_t)which*1048576);
        const int r0 = (bb>>5)*32, c0 = (bb&31)*32;
        const int lr = tid>>3, lc = (tid&7)*4;
        float4 v = *(const float4*)(in + (size_t)(r0+lr)*1024 + c0 + lc);
        t[lr][lc]=v.x; t[lr][lc+1]=v.y; t[lr][lc+2]=v.z; t[lr][lc+3]=v.w;
        __syncthreads();
        ushort4 o;
        o.x=f2bf(t[lc+0][lr]); o.y=f2bf(t[lc+1][lr]);
        o.z=f2bf(t[lc+2][lr]); o.w=f2bf(t[lc+3][lr]);
        *(ushort4*)(hi + (size_t)(c0+lr)*1024 + r0+lc) = o;
    } else if (bid < 12288){
        size_t i = ((size_t)(bid-4096)*256 + tid)*4;
        float4 v = *(const float4*)(X+i);
        ushort4 o; o.x=f2bf(v.x); o.y=f2bf(v.y); o.z=f2bf(v.z); o.w=f2bf(v.w);
        *(ushort4*)(Xb+i) = o;
    } else {
        int idx = (bid-12288)*256 + tid;          // 0..16383
        int e = idx&7, l = (idx>>3)&63, f = idx>>9;
        int nt = f>>1, ks = f&1;
        int d = 32*ks + 8*(l>>4) + e;
        int m = 16*nt + (l&15);
        pPh[idx] = f2bf(proj[d*256 + m]);
    }
}

// ============================================================================
// k_qkv: C = X @ {Wq,Wk,Wv}; GEMM core v2. grid (64,12) = 768 = 3 CU rounds.
// ============================================================================
__global__ __launch_bounds__(512,2) void k_qkv(const u16* __restrict__ Xb, const u16* __restrict__ WT,
        const float* __restrict__ bq, const float* __restrict__ bk, const float* __restrict__ bv,
        u16* __restrict__ Qb, u16* __restrict__ Kb, u16* __restrict__ VT){
    __shared__ u16 As[3*128*64];   // 48KB
    __shared__ u16 Bs[3*256*64];   // 96KB
    const int bx = blockIdx.x, y = blockIdx.y;
    const int wsel = y>>2, nb = y&3;
    const int tid = threadIdx.x, w = tid>>6, l = tid&63, g = l>>4, c = l&15;
    const int wr = w>>2, wc = w&3;
    const u16* Ap = Xb + (size_t)bx*128*1024;
    const u16* Bp = WT + (size_t)wsel*1048576 + (size_t)nb*256*1024;
    f32x4 acc[4][4];
    #pragma unroll
    for(int mt=0;mt<4;++mt)
        #pragma unroll
        for(int nt=0;nt<4;++nt) acc[mt][nt] = f32x4{0.f,0.f,0.f,0.f};

    GEMM_CORE_128x256(As, Bs, Ap, Bp, acc);

    const int n0 = nb*256 + 64*wc;    // col within this wsel's 1024
    const int b = bx>>5;
    if (wsel < 2){
        u16* Out = wsel ? Kb : Qb;
        const float* bias = wsel ? bk : bq;
        float bb[4];
        #pragma unroll
        for(int nt=0;nt<4;++nt) bb[nt] = bias[n0+16*nt+c];
        #pragma unroll
        for(int mt=0;mt<4;++mt){
            #pragma unroll
            for(int nt=0;nt<4;++nt)
                #pragma unroll
                for(int r=0;r<4;++r) acc[mt][nt][r] += bb[nt];
            // wave's 64 cols are one head -> norm over nt(4) x shfl16
            #pragma unroll
            for(int r=0;r<4;++r){
                float ss = 0.f;
                #pragma unroll
                for(int nt=0;nt<4;++nt){ float vv = acc[mt][nt][r]; ss += vv*vv; }
                ss += __shfl_xor(ss,1); ss += __shfl_xor(ss,2);
                ss += __shfl_xor(ss,4); ss += __shfl_xor(ss,8);
                float sc = 1.f/(sqrtf(ss)+1e-6f);
                #pragma unroll
                for(int nt=0;nt<4;++nt) acc[mt][nt][r] *= sc;
            }
            const int rowb = bx*128 + 64*wr + 16*mt + 4*g;
            #pragma unroll
            for(int nt=0;nt<4;++nt)
                #pragma unroll
                for(int r=0;r<4;++r)
                    Out[(size_t)(rowb+r)*1024 + n0 + 16*nt + c] = f2bf(acc[mt][nt][r]);
        }
    } else {
        const int h = nb*4 + wc;
        float bb[4];
        #pragma unroll
        for(int nt=0;nt<4;++nt) bb[nt] = bv[n0+16*nt+c];
        #pragma unroll
        for(int mt=0;mt<4;++mt)
            #pragma unroll
            for(int nt=0;nt<4;++nt){
                const int d = 16*nt + c;
                const int s0m = (bx&31)*128 + 64*wr + 16*mt + 4*g;
                ushort4 o;
                o.x = f2bf(acc[mt][nt][0]+bb[nt]); o.y = f2bf(acc[mt][nt][1]+bb[nt]);
                o.z = f2bf(acc[mt][nt][2]+bb[nt]); o.w = f2bf(acc[mt][nt][3]+bb[nt]);
                *(ushort4*)(VT + ((size_t)(b*16+h)*64 + d)*4096 + s0m) = o;
            }
    }
}

// ============================================================================
// k_kv v2 (round-15 proven): grid (8, 32), 512 thr = 8 waves. Split-K 8 chunks
// of 512 s; 4 t-iters of 128 s-rows. pPh staged in LDS once.
// ============================================================================
__global__ __launch_bounds__(512) void k_kv(const u16* __restrict__ Kb,
        const u16* __restrict__ pPh,
        const float* __restrict__ mask, const u16* __restrict__ VT,
        float* __restrict__ KVpart, float* __restrict__ Zpart){
    __shared__ u16 pps[16384];        // 32KB, linear copy of pPh
    __shared__ u16 phiT[256][136];    // [m][s 128], pad 136
    __shared__ u16 Vs[64][136];       // [d][s 128]
    __shared__ float zbuf[8][256];
    const int chunk = blockIdx.x, bh = blockIdx.y;
    const int b = bh>>4, h = bh&15;
    const int tid = threadIdx.x, w = tid>>6, l = tid&63, g = l>>4, c = l&15;
    // stage pps once
    #pragma unroll
    for(int j2=0;j2<4;++j2){
        const int base = (j2*8 + w)*512;
        GLOAD16(pps + base, pPh + base + l*8);
    }
    f32x4 kv[2][4];
    #pragma unroll
    for(int mt=0;mt<2;++mt) for(int dt=0;dt<4;++dt) kv[mt][dt] = f32x4{0.f,0.f,0.f,0.f};
    float zacc[16];
    #pragma unroll
    for(int nt=0;nt<16;++nt) zacc[nt]=0.f;
    const int vd = tid>>3, vs8 = (tid&7)*16;
    asm volatile("s_waitcnt vmcnt(0)" ::: "memory");
    __syncthreads();                       // pps staged
    for(int t=0;t<4;++t){
        const int s0 = chunk*512 + t*128;
        { // stage V tile [64 d][128 s] (reg path; 512 thr x 16 u16)
            const u16* pv = VT + ((size_t)bh*64 + vd)*4096 + s0 + vs8;
            uint4 v0 = *(const uint4*)pv, v1 = *(const uint4*)(pv+8);
            *(uint4*)&Vs[vd][vs8] = v0; *(uint4*)&Vs[vd][vs8+8] = v1;
        }
        // phase A: u = K_head @ proj (wave w -> s rows s0+16w..+15), pps-resident
        f32x4 ph[16];
        #pragma unroll
        for(int nt=0;nt<16;++nt) ph[nt] = f32x4{0.f,0.f,0.f,0.f};
        #pragma unroll
        for(int ks=0;ks<2;++ks){
            const int srow = s0 + 16*w + c;
            bf16x8 ah = *(const bf16x8*)(Kb + (size_t)(b*4096+srow)*1024 + h*64 + 32*ks + 8*g);
            #pragma unroll
            for(int nt=0;nt<16;++nt){
                bf16x8 bh8 = *(const bf16x8*)(pps + ((nt*2+ks)*64 + l)*8);
                ph[nt] = MFMA(ah, bh8, ph[nt]);
            }
        }
        float mk[4];
        #pragma unroll
        for(int r=0;r<4;++r) mk[r] = mask[b*4096 + s0 + 16*w + 4*g + r];
        #pragma unroll
        for(int nt=0;nt<16;++nt){
            float zs = 0.f;
            #pragma unroll
            for(int r=0;r<4;++r){
                float phv = __expf(ph[nt][r]-0.5f)*0.0625f*mk[r];
                phiT[c+16*nt][16*w+4*g+r] = f2bf(phv);
                zs += phv;
            }
            zacc[nt] += zs;
        }
        __syncthreads();               // phiT + Vs written
        // phase B: KV += phiT(A, m rows 32w..) x Vs(B, d cols), K=128
        #pragma unroll
        for(int ks=0;ks<4;++ks){
            bf16x8 afr[2], bfr[4];
            #pragma unroll
            for(int mt=0;mt<2;++mt) afr[mt] = *(const bf16x8*)&phiT[32*w+16*mt+c][32*ks+8*g];
            #pragma unroll
            for(int dt=0;dt<4;++dt) bfr[dt] = *(const bf16x8*)&Vs[16*dt+c][32*ks+8*g];
            #pragma unroll
            for(int mt=0;mt<2;++mt)
                #pragma unroll
                for(int dt=0;dt<4;++dt)
                    kv[mt][dt] = MFMA(afr[mt], bfr[dt], kv[mt][dt]);
        }
        __syncthreads();               // phase-B reads done before next overwrite
    }
    // Z partial
    #pragma unroll
    for(int nt=0;nt<16;++nt){
        float z = zacc[nt];
        z += __shfl_xor(z,16); z += __shfl_xor(z,32);
        if (g==0) zbuf[w][c+16*nt] = z;
    }
    __syncthreads();
    if (tid < 256){
        float z = 0.f;
        #pragma unroll
        for(int ww=0;ww<8;++ww) z += zbuf[ww][tid];
        Zpart[((size_t)bh*8+chunk)*256 + tid] = z;
    }
    float* kout = KVpart + ((size_t)bh*8+chunk)*16384;   // [256 m][64 d]
    #pragma unroll
    for(int mt=0;mt<2;++mt)
        #pragma unroll
        for(int dt=0;dt<4;++dt)
            #pragma unroll
            for(int r=0;r<4;++r)
                kout[(32*w+16*mt+4*g+r)*64 + 16*dt + c] = kv[mt][dt][r];
}

// ============================================================================
// k_kvreduce (round-15 proven): 512 blocks x 256 threads, one float4/thread.
// ============================================================================
__global__ __launch_bounds__(256) void k_kvreduce(const float* __restrict__ KVpart,
        const float* __restrict__ Zpart, u16* __restrict__ KVT, float* __restrict__ Z){
    const int gid = blockIdx.x*256 + threadIdx.x;      // 0..131071
    const int bh = gid >> 12;                          // 4096 float4 per bh
    const int i0 = (gid & 4095) * 4;                   // element idx in [256m][64d]
    float4 s = {0.f,0.f,0.f,0.f};
    const float* base = KVpart + (size_t)bh*8*16384 + i0;
    #pragma unroll
    for(int ch=0; ch<8; ++ch){
        float4 v = *(const float4*)(base + (size_t)ch*16384);
        s.x+=v.x; s.y+=v.y; s.z+=v.z; s.w+=v.w;
    }
    const int m = i0 >> 6, d = i0 & 63;                // 4 consecutive d, same m
    u16* dst = KVT + ((size_t)bh*64 + d)*256 + m;
    dst[0]   = f2bf(s.x);
    dst[256] = f2bf(s.y);
    dst[512] = f2bf(s.z);
    dst[768] = f2bf(s.w);
    if (gid < 8192){
        const int zbh = gid >> 8, zm = gid & 255;
        float z = 0.f;
        #pragma unroll
        for(int ch=0; ch<8; ++ch) z += Zpart[((size_t)zbh*8+ch)*256 + zm];
        Z[zbh*256 + zm] = z;
    }
}

// ============================================================================
// k_attn v2 (round-15 proven): grid (8, 32), 512 thr = 8 waves.
// KVT (32KB swizzled) + pPh (32KB) + Z staged in LDS once; 4 tiles x 128 rows.
// ============================================================================
__global__ __launch_bounds__(512) void k_attn(const u16* __restrict__ Qb,
        const u16* __restrict__ pPh,
        const u16* __restrict__ KVT, const float* __restrict__ Z, u16* __restrict__ attn){
    __shared__ u16 kvs[64*256];       // 32KB, row d, swizzled col-blocks
    __shared__ u16 pps[16384];        // 32KB, linear copy of pPh
    __shared__ u16 phi[128][264];     // 67.5KB
    __shared__ float Zs[256];
    const int bx = blockIdx.x, bh = blockIdx.y;
    const int b = bh>>4, h = bh&15;
    const int tid = threadIdx.x, w = tid>>6, l = tid&63, g = l>>4, c = l&15;
    if (tid < 256) Zs[tid] = Z[bh*256 + tid];
    // stage kvs: 32 gload units of 2 rows; dst linear, src col-block pre-swizzled
    #pragma unroll
    for(int j2=0;j2<4;++j2){
        const int base_row = (j2*8 + w)*2;
        const int row = base_row + (l>>5), cb = l&31;
        GLOAD16(kvs + base_row*256,
                KVT + (size_t)bh*16384 + row*256 + ((cb ^ (row&7))*8));
    }
    // stage pps: straight linear copy
    #pragma unroll
    for(int j2=0;j2<4;++j2){
        const int base = (j2*8 + w)*512;
        GLOAD16(pps + base, pPh + base + l*8);
    }
    asm volatile("s_waitcnt vmcnt(0)" ::: "memory");
    __syncthreads();

    for(int t=0;t<4;++t){
        const int s0 = bx*512 + t*128;
        // phiQ: u = Q_head @ proj (wave w -> s rows s0+16w .. +15)
        f32x4 ph[16];
        #pragma unroll
        for(int nt=0;nt<16;++nt) ph[nt] = f32x4{0.f,0.f,0.f,0.f};
        #pragma unroll
        for(int ks=0;ks<2;++ks){
            const int srow = s0 + 16*w + c;
            bf16x8 ah = *(const bf16x8*)(Qb + (size_t)(b*4096+srow)*1024 + h*64 + 32*ks + 8*g);
            #pragma unroll
            for(int nt=0;nt<16;++nt){
                bf16x8 bh8 = *(const bf16x8*)(pps + ((nt*2+ks)*64 + l)*8);
                ph[nt] = MFMA(ah, bh8, ph[nt]);
            }
        }
        float den[4] = {0.f,0.f,0.f,0.f};
        #pragma unroll
        for(int nt=0;nt<16;++nt){
            float zv = Zs[c+16*nt];
            #pragma unroll
            for(int r=0;r<4;++r){
                float phv = __expf(ph[nt][r]-0.5f)*0.0625f;
                den[r] += phv*zv;
                phi[16*w+4*g+r][c+16*nt] = f2bf(phv);
            }
        }
        #pragma unroll
        for(int r=0;r<4;++r){
            den[r] += __shfl_xor(den[r],1); den[r] += __shfl_xor(den[r],2);
            den[r] += __shfl_xor(den[r],4); den[r] += __shfl_xor(den[r],8);
            den[r] += 1e-6f;
        }
        __syncthreads();              // phi written
        f32x4 nm[4];
        #pragma unroll
        for(int dt=0;dt<4;++dt) nm[dt] = f32x4{0.f,0.f,0.f,0.f};
        #pragma unroll
        for(int j=0;j<8;++j){
            bf16x8 af = *(const bf16x8*)&phi[16*w+c][32*j+8*g];
            #pragma unroll
            for(int dt=0;dt<4;++dt){
                const int row = 16*dt + c, cb = 4*j + g;
                bf16x8 bfr = *(const bf16x8*)(kvs + row*256 + ((cb ^ (row&7))*8));
                nm[dt] = MFMA(af, bfr, nm[dt]);
            }
        }
        #pragma unroll
        for(int dt=0;dt<4;++dt)
            #pragma unroll
            for(int r=0;r<4;++r){
                const int srow = s0 + 16*w + 4*g + r;
                attn[(size_t)(b*4096+srow)*1024 + h*64 + 16*dt + c] = f2bf(nm[dt][r]*8.f/den[r]);
            }
        __syncthreads();              // phi reads done before next tile's writes
    }
}

// ============================================================================
// k_out: out = attn(bf16) @ WfT(bf16) + bf, fp32 out. GEMM core v2 (128x256).
// grid (64,4) = 256 = 1 exact CU round.
// ============================================================================
__global__ __launch_bounds__(512,2) void k_out(const u16* __restrict__ attn,
        const u16* __restrict__ Wh, const float* __restrict__ bfb, float* __restrict__ out){
    __shared__ u16 As[3*128*64];   // 48KB
    __shared__ u16 Bs[3*256*64];   // 96KB
    const int bx = blockIdx.x, by = blockIdx.y;
    const int tid = threadIdx.x, w = tid>>6, l = tid&63, g = l>>4, c = l&15;
    const int wr = w>>2, wc = w&3;
    const u16* Ap = attn + (size_t)bx*128*1024;
    const u16* Bp = Wh + (size_t)by*256*1024;
    f32x4 acc[4][4];
    #pragma unroll
    for(int mt=0;mt<4;++mt)
        #pragma unroll
        for(int nt=0;nt<4;++nt) acc[mt][nt] = f32x4{0.f,0.f,0.f,0.f};

    GEMM_CORE_128x256(As, Bs, Ap, Bp, acc);

    const int n0 = by*256 + 64*wc;
    #pragma unroll
    for(int mt=0;mt<4;++mt){
        const int rowb = bx*128 + 64*wr + 16*mt + 4*g;
        #pragma unroll
        for(int nt=0;nt<4;++nt){
            const float bb = bfb[n0+16*nt+c];
            #pragma unroll
            for(int r=0;r<4;++r)
                out[(size_t)(rowb+r)*1024 + n0 + 16*nt + c] = acc[mt][nt][r] + bb;
        }
    }
}

// ============================================================================
extern "C" void kernel_launch(void* const* d_in, const int* in_sizes, int n_in,
                              void* d_out, int out_size, void* d_ws, size_t ws_size,
                              hipStream_t stream){
    (void)in_sizes; (void)n_in; (void)out_size;
    const float* X    = (const float*)d_in[0];
    const float* mask = (const float*)d_in[1];
    const float* Wq   = (const float*)d_in[2];
    const float* bq   = (const float*)d_in[3];
    const float* Wk   = (const float*)d_in[4];
    const float* bk   = (const float*)d_in[5];
    const float* Wv   = (const float*)d_in[6];
    const float* bv   = (const float*)d_in[7];
    const float* Wf   = (const float*)d_in[8];
    const float* bfb  = (const float*)d_in[9];
    const float* proj = (const float*)d_in[10];
    float* out = (float*)d_out;

    char* w = (char*)d_ws;
    size_t off = 0;
    auto alloc = [&](size_t n)->void*{ void* p = w + off; off = (off + n + 255) & ~(size_t)255; return p; };
    u16*   Xb     = (u16*)  alloc((size_t)8192*1024*2);    // X bf16
    u16*   WT     = (u16*)  alloc((size_t)3*1048576*2);    // Wq,Wk,Wv transposed [n][k]
    u16*   Wfh    = (u16*)  alloc((size_t)1048576*2);      // WfT
    u16*   pPh    = (u16*)  alloc(16384*2);                // proj packed (bf16)
    u16*   Qb     = (u16*)  alloc((size_t)8192*1024*2);    // normalized Q bf16
    u16*   Kb     = (u16*)  alloc((size_t)8192*1024*2);    // normalized K bf16
    u16*   VT     = (u16*)  alloc((size_t)32*64*4096*2);   // V^T per head bf16
    float* KVpart = (float*)alloc((size_t)32*8*16384*4);   // split-K KV partials
    float* Zpart  = (float*)alloc((size_t)32*8*256*4);
    u16*   KVT    = (u16*)  alloc((size_t)32*64*256*2);    // KV^T [d][m] bf16
    float* Zr     = (float*)alloc((size_t)32*256*4);
    u16*   attnB  = (u16*)  alloc((size_t)8192*1024*2);    // attn bf16
    if (off > ws_size) return;  // ws too small: fail cleanly (output stays zero)

    k_prep<<<dim3(12352), 256, 0, stream>>>(X, Wq, Wk, Wv, Wf, proj, Xb, WT, Wfh, pPh);
    k_qkv<<<dim3(64,12), 512, 0, stream>>>(Xb, WT, bq, bk, bv, Qb, Kb, VT);
    k_kv<<<dim3(8,32), 512, 0, stream>>>(Kb, pPh, mask, VT, KVpart, Zpart);
    k_kvreduce<<<dim3(512), 256, 0, stream>>>(KVpart, Zpart, KVT, Zr);
    k_attn<<<dim3(8,32), 512, 0, stream>>>(Qb, pPh, KVT, Zr, attnB);
    k_out<<<dim3(64,4), 512, 0, stream>>>(attnB, Wfh, bfb, out);
}